// Round 1
// baseline (115.762 us; speedup 1.0000x reference)
//
#include <hip/hip_runtime.h>
#include <math.h>

#define BM 60      // modes per batch
#define TT 80      // timesteps
#define NAG 128    // agents
#define NLANES 64
#define NPTS 20
#define NLP (NLANES * NPTS)  // 1280 lane points
#define BIGF 1000000.0f

// Kernel 1: per-(b,m) partial score (everything except the softmax term).
// score_part = 0.1*comfort + 0.5*progress + 1.0*collision + 0.3*drivable
__global__ __launch_bounds__(256) void score_kernel(
    const float* __restrict__ trajs,   // (B, M, T, 3)
    const float* __restrict__ agents,  // (B, NAG, 4)
    const float* __restrict__ amask,   // (B, NAG)
    const float* __restrict__ lanes,   // (B, NLANES, NPTS, 3)
    const float* __restrict__ lmask,   // (B, NLANES)
    float* __restrict__ scores)        // (B*M,)
{
    __shared__ float s_ex[TT], s_ey[TT];
    __shared__ float s_ax[NAG], s_ay[NAG], s_ap[NAG];
    __shared__ float s_lx[NLP], s_ly[NLP], s_lp[NLP];
    __shared__ float s_cred[8], s_dred[8];
    __shared__ float s_jerk;

    const int bm  = blockIdx.x;       // b*M + m
    const int b   = bm / BM;
    const int tid = threadIdx.x;

    const float* tr = trajs + (size_t)bm * TT * 3;
    for (int i = tid; i < TT; i += 256) {
        s_ex[i] = tr[i * 3 + 0];
        s_ey[i] = tr[i * 3 + 1];
    }
    for (int i = tid; i < NAG; i += 256) {
        s_ax[i] = agents[((size_t)b * NAG + i) * 4 + 0];
        s_ay[i] = agents[((size_t)b * NAG + i) * 4 + 1];
        s_ap[i] = (1.0f - amask[b * NAG + i]) * BIGF;
    }
    for (int i = tid; i < NLP; i += 256) {
        s_lx[i] = lanes[((size_t)b * NLP + i) * 3 + 0];
        s_ly[i] = lanes[((size_t)b * NLP + i) * 3 + 1];
        s_lp[i] = (1.0f - lmask[b * NLANES + i / NPTS]) * BIGF;
    }
    if (tid == 0) s_jerk = 0.0f;
    __syncthreads();

    // comfort: 77 jerk norms, jerk[t] = x[t+3] - 3x[t+2] + 3x[t+1] - x[t]
    if (tid < TT - 3) {
        float jx = s_ex[tid + 3] - 3.0f * s_ex[tid + 2] + 3.0f * s_ex[tid + 1] - s_ex[tid];
        float jy = s_ey[tid + 3] - 3.0f * s_ey[tid + 2] + 3.0f * s_ey[tid + 1] - s_ey[tid];
        atomicAdd(&s_jerk, sqrtf(jx * jx + jy * jy));
    }

    // collision + drivable: 8 groups of 32 lanes; group g handles t = g + 8*r.
    const int g = tid >> 5;
    const int l = tid & 31;
    int ccoll = 0, cdriv = 0;
    for (int r = 0; r < TT / 8; ++r) {
        const int t = g + 8 * r;
        const float ex = s_ex[t], ey = s_ey[t];

        float m2 = 1e30f;  // min squared agent distance
        for (int i = l; i < NAG; i += 32) {
            float dx = ex - s_ax[i];
            float dy = ey - s_ay[i];
            m2 = fminf(m2, fmaf(dy, dy, dx * dx) + s_ap[i]);
        }
        float m3 = 1e30f;  // min squared lane-point distance
        for (int i = l; i < NLP; i += 32) {
            float dx = ex - s_lx[i];
            float dy = ey - s_ly[i];
            m3 = fminf(m3, fmaf(dy, dy, dx * dx) + s_lp[i]);
        }
        for (int off = 16; off > 0; off >>= 1) {
            m2 = fminf(m2, __shfl_xor(m2, off, 32));
            m3 = fminf(m3, __shfl_xor(m3, off, 32));
        }
        if (l == 0) {
            // min(d) < 2  <=>  min(d^2) < 4 ; min(d) > 3 <=> min(d^2) > 9
            if (m2 < 4.0f) ccoll++;
            if (m3 > 9.0f) cdriv++;
        }
    }
    if (l == 0) { s_cred[g] = (float)ccoll; s_dred[g] = (float)cdriv; }
    __syncthreads();

    if (tid == 0) {
        float coll = 0.0f, driv = 0.0f;
        for (int i = 0; i < 8; ++i) { coll += s_cred[i]; driv += s_dred[i]; }
        float comfort  = -(s_jerk / (float)(TT - 3));
        float progress = tr[(TT - 1) * 3 + 0];
        float score = 0.1f * comfort + 0.5f * progress
                    - 1.0f * (coll / (float)TT)
                    - 0.3f * (driv / (float)TT);
        scores[bm] = score;
    }
}

// Kernel 2: per-b softmax over M=60 logits, add partial scores, argmax
// (first-index tie-break like jnp.argmax), emit winning trajectory + index.
__global__ __launch_bounds__(64) void select_kernel(
    const float* __restrict__ logits,  // (B, M)
    const float* __restrict__ trajs,   // (B, M, T, 3)
    const float* __restrict__ scores,  // (B*M,)
    float* __restrict__ out,           // traj (B*T*3) then idx (B)
    int B)
{
    const int b    = blockIdx.x;
    const int lane = threadIdx.x;

    float lg = (lane < BM) ? logits[b * BM + lane] : -1e30f;
    float mx = lg;
    for (int off = 32; off > 0; off >>= 1) mx = fmaxf(mx, __shfl_xor(mx, off, 64));
    float e = (lane < BM) ? expf(lg - mx) : 0.0f;
    float sum = e;
    for (int off = 32; off > 0; off >>= 1) sum += __shfl_xor(sum, off, 64);

    float sc = (lane < BM) ? (e / sum + scores[b * BM + lane]) : -1e30f;
    int idx = lane;
    for (int off = 32; off > 0; off >>= 1) {
        float os = __shfl_xor(sc, off, 64);
        int   oi = __shfl_xor(idx, off, 64);
        if (os > sc || (os == sc && oi < idx)) { sc = os; idx = oi; }
    }
    // all 64 lanes now agree on idx
    const float* src = trajs + ((size_t)b * BM + idx) * TT * 3;
    for (int k = lane; k < TT * 3; k += 64) out[b * TT * 3 + k] = src[k];
    if (lane == 0) out[B * TT * 3 + b] = (float)idx;
}

extern "C" void kernel_launch(void* const* d_in, const int* in_sizes, int n_in,
                              void* d_out, int out_size, void* d_ws, size_t ws_size,
                              hipStream_t stream) {
    const float* logits = (const float*)d_in[0];
    const float* trajs  = (const float*)d_in[1];
    const float* agents = (const float*)d_in[2];
    const float* amask  = (const float*)d_in[3];
    const float* lanes  = (const float*)d_in[4];
    const float* lmask  = (const float*)d_in[5];

    const int B = in_sizes[0] / BM;  // 16
    float* scores = (float*)d_ws;    // B*M floats of scratch
    float* out    = (float*)d_out;

    score_kernel<<<B * BM, 256, 0, stream>>>(trajs, agents, amask, lanes, lmask, scores);
    select_kernel<<<B, 64, 0, stream>>>(logits, trajs, scores, out, B);
}

// Round 2
// 84.796 us; speedup vs baseline: 1.3652x; 1.3652x over previous
//
#include <hip/hip_runtime.h>
#include <math.h>

#define BM 60      // modes per batch
#define TT 80      // timesteps
#define NAG 128    // agents
#define NLANES 64
#define NPTS 20
#define NLP (NLANES * NPTS)  // 1280 lane points
#define PPL (NLP / 64)       // 20 lane-points per lane
#define APL (NAG / 64)       // 2 agents per lane

// One wave per (b,m). All points register-resident; thresholds via ballot.
__global__ __launch_bounds__(64) void score_kernel(
    const float* __restrict__ trajs,   // (B, M, T, 3)
    const float* __restrict__ agents,  // (B, NAG, 4)
    const float* __restrict__ amask,   // (B, NAG)
    const float* __restrict__ lanes,   // (B, NLANES, NPTS, 3)
    const float* __restrict__ lmask,   // (B, NLANES)
    float* __restrict__ scores)        // (B*M,)
{
    __shared__ float s_ex[TT], s_ey[TT];

    const int bm   = blockIdx.x;   // b*M + m
    const int b    = bm / BM;
    const int lane = threadIdx.x;  // 0..63

    const float* tr = trajs + (size_t)bm * TT * 3;

    // Stage ego xy into LDS (read later via free same-address broadcast).
    for (int i = lane; i < TT; i += 64) {
        s_ex[i] = tr[i * 3 + 0];
        s_ey[i] = tr[i * 3 + 1];
    }

    // Lane-private agents/points in registers; fold mask into x-coordinate.
    // masked => x += 1e8 => d^2 ~ 1e16: never < 4, always > 9. Same booleans
    // as the reference's +1e6-on-distance penalty.
    float ax[APL], ay[APL];
#pragma unroll
    for (int k = 0; k < APL; ++k) {
        const int i = lane + 64 * k;
        const float off = (1.0f - amask[b * NAG + i]) * 1e8f;
        ax[k] = agents[((size_t)b * NAG + i) * 4 + 0] + off;
        ay[k] = agents[((size_t)b * NAG + i) * 4 + 1];
    }
    float px[PPL], py[PPL];
#pragma unroll
    for (int k = 0; k < PPL; ++k) {
        const int i = lane + 64 * k;
        const float off = (1.0f - lmask[b * NLANES + i / NPTS]) * 1e8f;
        px[k] = lanes[((size_t)b * NLP + i) * 3 + 0] + off;
        py[k] = lanes[((size_t)b * NLP + i) * 3 + 1];
    }

    __syncthreads();

    int ccoll = 0, cdriv = 0;
    for (int r = 0; r < TT / 8; ++r) {
        float ex[8], ey[8], m2[8], m3[8];
#pragma unroll
        for (int j = 0; j < 8; ++j) {
            ex[j] = s_ex[r * 8 + j];   // broadcast read
            ey[j] = s_ey[r * 8 + j];
            m2[j] = 1e30f;
            m3[j] = 1e30f;
        }
#pragma unroll
        for (int k = 0; k < APL; ++k) {
#pragma unroll
            for (int j = 0; j < 8; ++j) {
                const float dx = ex[j] - ax[k];
                const float dy = ey[j] - ay[k];
                m2[j] = fminf(m2[j], fmaf(dx, dx, dy * dy));
            }
        }
#pragma unroll
        for (int k = 0; k < PPL; ++k) {
#pragma unroll
            for (int j = 0; j < 8; ++j) {
                const float dx = ex[j] - px[k];
                const float dy = ey[j] - py[k];
                m3[j] = fminf(m3[j], fmaf(dx, dx, dy * dy));
            }
        }
#pragma unroll
        for (int j = 0; j < 8; ++j) {
            // min(d) < 2  <=> exists d^2 < 4 ; min(d) > 3 <=> no d^2 <= 9
            ccoll += (__ballot(m2[j] < 4.0f) != 0ull) ? 1 : 0;
            cdriv += (__ballot(m3[j] <= 9.0f) == 0ull) ? 1 : 0;
        }
    }

    // comfort: jerk[t] = x[t+3] - 3x[t+2] + 3x[t+1] - x[t], t in [0,77)
    float jsum = 0.0f;
    if (lane < TT - 3) {
        const float jx = s_ex[lane + 3] - 3.0f * s_ex[lane + 2] + 3.0f * s_ex[lane + 1] - s_ex[lane];
        const float jy = s_ey[lane + 3] - 3.0f * s_ey[lane + 2] + 3.0f * s_ey[lane + 1] - s_ey[lane];
        jsum = sqrtf(jx * jx + jy * jy);
    }
    {
        const int t2 = lane + 64;
        if (t2 < TT - 3) {
            const float jx = s_ex[t2 + 3] - 3.0f * s_ex[t2 + 2] + 3.0f * s_ex[t2 + 1] - s_ex[t2];
            const float jy = s_ey[t2 + 3] - 3.0f * s_ey[t2 + 2] + 3.0f * s_ey[t2 + 1] - s_ey[t2];
            jsum += sqrtf(jx * jx + jy * jy);
        }
    }
    for (int off = 32; off > 0; off >>= 1) jsum += __shfl_xor(jsum, off, 64);

    if (lane == 0) {
        const float comfort  = -(jsum / (float)(TT - 3));
        const float progress = tr[(TT - 1) * 3 + 0];
        scores[bm] = 0.1f * comfort + 0.5f * progress
                   - 1.0f * ((float)ccoll / (float)TT)
                   - 0.3f * ((float)cdriv / (float)TT);
    }
}

// Per-b softmax over M=60 logits, add partial scores, argmax (first-index
// tie-break like jnp.argmax), emit winning trajectory + index.
__global__ __launch_bounds__(64) void select_kernel(
    const float* __restrict__ logits,  // (B, M)
    const float* __restrict__ trajs,   // (B, M, T, 3)
    const float* __restrict__ scores,  // (B*M,)
    float* __restrict__ out,           // traj (B*T*3) then idx (B)
    int B)
{
    const int b    = blockIdx.x;
    const int lane = threadIdx.x;

    float lg = (lane < BM) ? logits[b * BM + lane] : -1e30f;
    float mx = lg;
    for (int off = 32; off > 0; off >>= 1) mx = fmaxf(mx, __shfl_xor(mx, off, 64));
    float e = (lane < BM) ? expf(lg - mx) : 0.0f;
    float sum = e;
    for (int off = 32; off > 0; off >>= 1) sum += __shfl_xor(sum, off, 64);

    float sc = (lane < BM) ? (e / sum + scores[b * BM + lane]) : -1e30f;
    int idx = lane;
    for (int off = 32; off > 0; off >>= 1) {
        float os = __shfl_xor(sc, off, 64);
        int   oi = __shfl_xor(idx, off, 64);
        if (os > sc || (os == sc && oi < idx)) { sc = os; idx = oi; }
    }
    const float* src = trajs + ((size_t)b * BM + idx) * TT * 3;
    for (int k = lane; k < TT * 3; k += 64) out[b * TT * 3 + k] = src[k];
    if (lane == 0) out[B * TT * 3 + b] = (float)idx;
}

extern "C" void kernel_launch(void* const* d_in, const int* in_sizes, int n_in,
                              void* d_out, int out_size, void* d_ws, size_t ws_size,
                              hipStream_t stream) {
    const float* logits = (const float*)d_in[0];
    const float* trajs  = (const float*)d_in[1];
    const float* agents = (const float*)d_in[2];
    const float* amask  = (const float*)d_in[3];
    const float* lanes  = (const float*)d_in[4];
    const float* lmask  = (const float*)d_in[5];

    const int B = in_sizes[0] / BM;  // 16
    float* scores = (float*)d_ws;    // B*M floats of scratch
    float* out    = (float*)d_out;

    score_kernel<<<B * BM, 64, 0, stream>>>(trajs, agents, amask, lanes, lmask, scores);
    select_kernel<<<B, 64, 0, stream>>>(logits, trajs, scores, out, B);
}

// Round 3
// 77.379 us; speedup vs baseline: 1.4960x; 1.0959x over previous
//
#include <hip/hip_runtime.h>
#include <math.h>

#define BM 60      // modes per batch
#define TT 80      // timesteps
#define NAG 128    // agents
#define NLANES 64
#define NPTS 20
#define NLP (NLANES * NPTS)  // 1280 lane points
#define PPL (NLP / 64)       // 20 lane-points per lane
#define APL (NAG / 64)       // 2 agents per lane

// One block of 2 waves per (b,m); wave h handles t in [40h, 40h+40).
// Points register-resident with distance expansion:
//   d^2 = c_t + s,  s = q_p - 2*ex*px - 2*ey*py,  q_p = px^2+py^2
// so inner eval is fma,fma,fmin (3 VALU) and thresholds fold into 4-c_t / 9-c_t.
__global__ __launch_bounds__(128) void score_kernel(
    const float* __restrict__ trajs,   // (B, M, T, 3)
    const float* __restrict__ agents,  // (B, NAG, 4)
    const float* __restrict__ amask,   // (B, NAG)
    const float* __restrict__ lanes,   // (B, NLANES, NPTS, 3)
    const float* __restrict__ lmask,   // (B, NLANES)
    float* __restrict__ scores)        // (B*M,)
{
    __shared__ float s_ex[TT], s_ey[TT];
    __shared__ float s_jerk;
    __shared__ float s_cc[2], s_cd[2];

    const int bm   = blockIdx.x;       // b*M + m
    const int b    = bm / BM;
    const int tid  = threadIdx.x;      // 0..127
    const int w    = tid >> 6;         // wave 0/1
    const int lane = tid & 63;

    const float* tr = trajs + (size_t)bm * TT * 3;
    for (int i = tid; i < TT; i += 128) {
        s_ex[i] = tr[i * 3 + 0];
        s_ey[i] = tr[i * 3 + 1];
    }
    if (tid == 0) s_jerk = 0.0f;

    // Lane-private points; mask folded into x (+1e8 => s ~ 1e16, never passes
    // either threshold — same booleans as reference's +1e6 distance penalty).
    float ax[APL], ay[APL], aq[APL];
#pragma unroll
    for (int k = 0; k < APL; ++k) {
        const int i = lane + 64 * k;
        const float off = (1.0f - amask[b * NAG + i]) * 1e8f;
        const float x = agents[((size_t)b * NAG + i) * 4 + 0] + off;
        const float y = agents[((size_t)b * NAG + i) * 4 + 1];
        ax[k] = x; ay[k] = y; aq[k] = fmaf(x, x, y * y);
    }
    float px[PPL], py[PPL], pq[PPL];
#pragma unroll
    for (int k = 0; k < PPL; ++k) {
        const int i = lane + 64 * k;
        const float off = (1.0f - lmask[b * NLANES + i / NPTS]) * 1e8f;
        const float x = lanes[((size_t)b * NLP + i) * 3 + 0] + off;
        const float y = lanes[((size_t)b * NLP + i) * 3 + 1];
        px[k] = x; py[k] = y; pq[k] = fmaf(x, x, y * y);
    }

    __syncthreads();

    // comfort: jerk[t] = x[t+3] - 3x[t+2] + 3x[t+1] - x[t], t in [0,77)
    float jsum = 0.0f;
    if (tid < TT - 3) {
        const float jx = s_ex[tid + 3] - 3.0f * s_ex[tid + 2] + 3.0f * s_ex[tid + 1] - s_ex[tid];
        const float jy = s_ey[tid + 3] - 3.0f * s_ey[tid + 2] + 3.0f * s_ey[tid + 1] - s_ey[tid];
        jsum = sqrtf(jx * jx + jy * jy);
    }
    for (int off = 32; off > 0; off >>= 1) jsum += __shfl_xor(jsum, off, 64);
    if (lane == 0 && jsum != 0.0f) atomicAdd(&s_jerk, jsum);
    if (lane == 0 && jsum == 0.0f) atomicAdd(&s_jerk, 0.0f);  // keep both waves uniform

    int ccoll = 0, cdriv = 0;
    const int t0 = w * (TT / 2);
    for (int r = 0; r < (TT / 2) / 8; ++r) {
        float mx8[8], my8[8], thrA[8], thrB[8], m2[8], m3[8];
#pragma unroll
        for (int j = 0; j < 8; ++j) {
            const float ex = s_ex[t0 + r * 8 + j];   // broadcast read
            const float ey = s_ey[t0 + r * 8 + j];
            const float c  = fmaf(ex, ex, ey * ey);
            mx8[j]  = -2.0f * ex;
            my8[j]  = -2.0f * ey;
            thrA[j] = 4.0f - c;
            thrB[j] = 9.0f - c;
            m2[j] = 1e30f;
            m3[j] = 1e30f;
        }
#pragma unroll
        for (int k = 0; k < APL; ++k) {
#pragma unroll
            for (int j = 0; j < 8; ++j) {
                float v = fmaf(my8[j], ay[k], aq[k]);
                v = fmaf(mx8[j], ax[k], v);
                m2[j] = fminf(m2[j], v);
            }
        }
#pragma unroll
        for (int k = 0; k < PPL; ++k) {
#pragma unroll
            for (int j = 0; j < 8; ++j) {
                float v = fmaf(my8[j], py[k], pq[k]);
                v = fmaf(mx8[j], px[k], v);
                m3[j] = fminf(m3[j], v);
            }
        }
#pragma unroll
        for (int j = 0; j < 8; ++j) {
            // min d^2 < 4  <=> exists s < 4-c ; min d^2 > 9 <=> no s <= 9-c
            ccoll += (__ballot(m2[j] < thrA[j]) != 0ull) ? 1 : 0;
            cdriv += (__ballot(m3[j] <= thrB[j]) == 0ull) ? 1 : 0;
        }
    }
    if (lane == 0) { s_cc[w] = (float)ccoll; s_cd[w] = (float)cdriv; }
    __syncthreads();

    if (tid == 0) {
        const float coll = s_cc[0] + s_cc[1];
        const float driv = s_cd[0] + s_cd[1];
        const float comfort  = -(s_jerk / (float)(TT - 3));
        const float progress = tr[(TT - 1) * 3 + 0];
        scores[bm] = 0.1f * comfort + 0.5f * progress
                   - 1.0f * (coll / (float)TT)
                   - 0.3f * (driv / (float)TT);
    }
}

// Per-b softmax over M=60 logits, add partial scores, argmax (first-index
// tie-break like jnp.argmax), emit winning trajectory + index.
__global__ __launch_bounds__(64) void select_kernel(
    const float* __restrict__ logits,  // (B, M)
    const float* __restrict__ trajs,   // (B, M, T, 3)
    const float* __restrict__ scores,  // (B*M,)
    float* __restrict__ out,           // traj (B*T*3) then idx (B)
    int B)
{
    const int b    = blockIdx.x;
    const int lane = threadIdx.x;

    float lg = (lane < BM) ? logits[b * BM + lane] : -1e30f;
    float mx = lg;
    for (int off = 32; off > 0; off >>= 1) mx = fmaxf(mx, __shfl_xor(mx, off, 64));
    float e = (lane < BM) ? expf(lg - mx) : 0.0f;
    float sum = e;
    for (int off = 32; off > 0; off >>= 1) sum += __shfl_xor(sum, off, 64);

    float sc = (lane < BM) ? (e / sum + scores[b * BM + lane]) : -1e30f;
    int idx = lane;
    for (int off = 32; off > 0; off >>= 1) {
        float os = __shfl_xor(sc, off, 64);
        int   oi = __shfl_xor(idx, off, 64);
        if (os > sc || (os == sc && oi < idx)) { sc = os; idx = oi; }
    }
    const float* src = trajs + ((size_t)b * BM + idx) * TT * 3;
    for (int k = lane; k < TT * 3; k += 64) out[b * TT * 3 + k] = src[k];
    if (lane == 0) out[B * TT * 3 + b] = (float)idx;
}

extern "C" void kernel_launch(void* const* d_in, const int* in_sizes, int n_in,
                              void* d_out, int out_size, void* d_ws, size_t ws_size,
                              hipStream_t stream) {
    const float* logits = (const float*)d_in[0];
    const float* trajs  = (const float*)d_in[1];
    const float* agents = (const float*)d_in[2];
    const float* amask  = (const float*)d_in[3];
    const float* lanes  = (const float*)d_in[4];
    const float* lmask  = (const float*)d_in[5];

    const int B = in_sizes[0] / BM;  // 16
    float* scores = (float*)d_ws;    // B*M floats of scratch
    float* out    = (float*)d_out;

    score_kernel<<<B * BM, 128, 0, stream>>>(trajs, agents, amask, lanes, lmask, scores);
    select_kernel<<<B, 64, 0, stream>>>(logits, trajs, scores, out, B);
}